// Round 2
// baseline (249.656 us; speedup 1.0000x reference)
//
#include <hip/hip_runtime.h>
#include <math.h>

// Problem constants
#define M_TOKENS 16384               // B*S = 4*4096
#define E_EXPERTS 64
#define K_DIM 2048
#define KSPLIT 4
#define KCHUNK (K_DIM / KSPLIT)      // 512
#define BK 64                        // k-depth per LDS stage
#define NSTAGE (KCHUNK / BK)         // 8
#define TPB 128                      // tokens per block
#define PSTRIDE (KSPLIT * E_EXPERTS) // 256 floats per token in partials

// ---------------------------------------------------------------------------
// Gates kernel. Grid: (M/TPB)*KSPLIT blocks of 256 threads (4 waves).
// Wave w: token-half (w&1), expert-half (w>>1) -> 32 fp32 accumulators/lane,
// W row-half is wave-uniform -> scalar loads, v_fmac v,s,v.
// x staged via LDS transposed [BK][TPB+1]: global float4 coalesced loads,
// LDS reads 64-consecutive-lane (2-way bank alias = free).
// Next-stage global loads issued before current compute to hide HBM latency.
// Partials: part[token][kc*64 + e]  (contiguous per token -> float4 I/O).
// ---------------------------------------------------------------------------
__global__ __launch_bounds__(256) void gates_kernel(
    const float* __restrict__ x, const float* __restrict__ W,
    float* __restrict__ part) {
  __shared__ float xT[BK][TPB + 1];

  const int bid = blockIdx.x;
  const int kc = bid & (KSPLIT - 1);
  const int tg = bid >> 2;           // token group
  const int tok0 = tg * TPB;
  const int kbase = kc * KCHUNK;

  const int tid = threadIdx.x;
  const int lane = tid & 63;
  const int wave = __builtin_amdgcn_readfirstlane(tid >> 6);
  const int th = wave & 1;           // token half
  const int eh = wave >> 1;          // expert half
  const int mytok = th * 64 + lane;  // 0..127 within block

  float4 stg[8];
  float acc[32];
#pragma unroll
  for (int e = 0; e < 32; ++e) acc[e] = 0.0f;

  // tile = TPB rows x BK floats = 2048 float4; thread handles f = tid + 256*j
  // row = f>>4 (16 float4 per row), c4 = f&15. 16 consecutive tids = one row.
#define STAGE_LOAD(sidx)                                                      \
  do {                                                                        \
    const float* xs = x + (size_t)tok0 * K_DIM + kbase + (sidx) * BK;         \
    _Pragma("unroll") for (int j = 0; j < 8; ++j) {                           \
      int f = tid + 256 * j;                                                  \
      int row = f >> 4, c4 = f & 15;                                          \
      stg[j] = *reinterpret_cast<const float4*>(xs + (size_t)row * K_DIM +    \
                                                c4 * 4);                      \
    }                                                                         \
  } while (0)

#define STAGE_WRITE()                                                         \
  do {                                                                        \
    _Pragma("unroll") for (int j = 0; j < 8; ++j) {                           \
      int f = tid + 256 * j;                                                  \
      int row = f >> 4, c4 = f & 15;                                          \
      xT[c4 * 4 + 0][row] = stg[j].x;                                         \
      xT[c4 * 4 + 1][row] = stg[j].y;                                         \
      xT[c4 * 4 + 2][row] = stg[j].z;                                         \
      xT[c4 * 4 + 3][row] = stg[j].w;                                         \
    }                                                                         \
  } while (0)

  STAGE_LOAD(0);
  STAGE_WRITE();
  __syncthreads();

  for (int s = 0; s < NSTAGE; ++s) {
    if (s + 1 < NSTAGE) STAGE_LOAD(s + 1);  // in flight during compute

    const float* wbase = W + (size_t)(kbase + s * BK) * E_EXPERTS + eh * 32;
#pragma unroll
    for (int k = 0; k < BK; ++k) {
      float xk = xT[k][mytok];
#pragma unroll
      for (int e = 0; e < 32; ++e)
        acc[e] = fmaf(xk, wbase[k * E_EXPERTS + e], acc[e]);
    }

    if (s + 1 < NSTAGE) {
      __syncthreads();   // everyone done reading xT
      STAGE_WRITE();
      __syncthreads();   // new tile visible
    }
  }

  // epilogue: 8 float4 stores, contiguous 32 floats per lane
  float* p = part + (size_t)(tok0 + mytok) * PSTRIDE + kc * E_EXPERTS + eh * 32;
#pragma unroll
  for (int e4 = 0; e4 < 8; ++e4) {
    float4 v = make_float4(acc[e4 * 4 + 0], acc[e4 * 4 + 1],
                           acc[e4 * 4 + 2], acc[e4 * 4 + 3]);
    *reinterpret_cast<float4*>(p + e4 * 4) = v;
  }
#undef STAGE_LOAD
#undef STAGE_WRITE
}

// ---------------------------------------------------------------------------
// Reduce + bias + top-2 + softmax. Thread = token; 64 float4 loads/thread,
// per-thread contiguous 1KB (full line use, deep MLP).
// Sum order matches round-1 (bias first, then kc ascending; fmaf chain per
// chunk is k-ascending in gates_kernel) to preserve the absmax=0 behavior.
// ---------------------------------------------------------------------------
__global__ __launch_bounds__(256) void reduce_topk_kernel(
    const float* __restrict__ part, const float* __restrict__ bias,
    float* __restrict__ out) {
  const int t = blockIdx.x * 256 + threadIdx.x;
  const float4* p = reinterpret_cast<const float4*>(part + (size_t)t * PSTRIDE);
  const float4* b4 = reinterpret_cast<const float4*>(bias);

  float m1 = -INFINITY, m2 = -INFINITY;
  int i1 = 0, i2 = 0;

#pragma unroll 4
  for (int e4 = 0; e4 < 16; ++e4) {
    float4 a = p[e4];        // kc = 0
    float4 b = p[16 + e4];   // kc = 1
    float4 c = p[32 + e4];   // kc = 2
    float4 d = p[48 + e4];   // kc = 3
    float4 bb = b4[e4];
    float g[4];
    g[0] = bb.x + a.x; g[0] += b.x; g[0] += c.x; g[0] += d.x;
    g[1] = bb.y + a.y; g[1] += b.y; g[1] += c.y; g[1] += d.y;
    g[2] = bb.z + a.z; g[2] += b.z; g[2] += c.z; g[2] += d.z;
    g[3] = bb.w + a.w; g[3] += b.w; g[3] += c.w; g[3] += d.w;
#pragma unroll
    for (int j = 0; j < 4; ++j) {
      int e = e4 * 4 + j;
      if (g[j] > m1) {
        m2 = m1; i2 = i1;
        m1 = g[j]; i1 = e;
      } else if (g[j] > m2) {
        m2 = g[j]; i2 = e;
      }
    }
  }

  float w0 = 1.0f / (1.0f + expf(m2 - m1));
  out[2 * t + 0] = w0;
  out[2 * t + 1] = 1.0f - w0;
  float* oidx = out + 2 * (size_t)M_TOKENS;
  oidx[2 * t + 0] = (float)i1;
  oidx[2 * t + 1] = (float)i2;
}

// ---------------------------------------------------------------------------
// Fallback (proven correct in round 1): fully fused, no workspace.
// ---------------------------------------------------------------------------
__global__ __launch_bounds__(64) void router_fused_kernel(
    const float* __restrict__ x, const float* __restrict__ W,
    const float* __restrict__ bias, float* __restrict__ out) {
  const int t = blockIdx.x * 64 + threadIdx.x;
  const float* xrow = x + (size_t)t * K_DIM;

  float acc[E_EXPERTS];
#pragma unroll
  for (int e = 0; e < E_EXPERTS; ++e) acc[e] = 0.0f;

  for (int k4 = 0; k4 < K_DIM; k4 += 4) {
    float4 xv = *reinterpret_cast<const float4*>(xrow + k4);
    float xs[4] = {xv.x, xv.y, xv.z, xv.w};
#pragma unroll
    for (int kk = 0; kk < 4; ++kk) {
      const float* wrow = W + (size_t)(k4 + kk) * E_EXPERTS;
#pragma unroll
      for (int e = 0; e < E_EXPERTS; ++e) acc[e] = fmaf(xs[kk], wrow[e], acc[e]);
    }
  }

  float m1 = -INFINITY, m2 = -INFINITY;
  int i1 = 0, i2 = 0;
#pragma unroll
  for (int e = 0; e < E_EXPERTS; ++e) {
    float g = acc[e] + bias[e];
    if (g > m1) {
      m2 = m1; i2 = i1;
      m1 = g; i1 = e;
    } else if (g > m2) {
      m2 = g; i2 = e;
    }
  }

  float w0 = 1.0f / (1.0f + expf(m2 - m1));
  out[2 * t + 0] = w0;
  out[2 * t + 1] = 1.0f - w0;
  float* oidx = out + 2 * (size_t)M_TOKENS;
  oidx[2 * t + 0] = (float)i1;
  oidx[2 * t + 1] = (float)i2;
}

extern "C" void kernel_launch(void* const* d_in, const int* in_sizes, int n_in,
                              void* d_out, int out_size, void* d_ws, size_t ws_size,
                              hipStream_t stream) {
  const float* x = (const float*)d_in[0];
  const float* W = (const float*)d_in[1];
  const float* b = (const float*)d_in[2];
  float* out = (float*)d_out;

  const size_t need = (size_t)M_TOKENS * PSTRIDE * sizeof(float);
  if (ws_size >= need) {
    float* part = (float*)d_ws;
    gates_kernel<<<(M_TOKENS / TPB) * KSPLIT, 256, 0, stream>>>(x, W, part);
    reduce_topk_kernel<<<M_TOKENS / 256, 256, 0, stream>>>(part, b, out);
  } else {
    router_fused_kernel<<<M_TOKENS / 64, 64, 0, stream>>>(x, W, b, out);
  }
}

// Round 3
// 85.229 us; speedup vs baseline: 2.9292x; 2.9292x over previous
//
#include <hip/hip_runtime.h>
#include <math.h>

// Problem constants
#define M_TOKENS 16384               // B*S = 4*4096
#define E_EXPERTS 64
#define K_DIM 2048
#define KSPLIT 4
#define KCHUNK (K_DIM / KSPLIT)      // 512
#define ESPLIT 4
#define EPW (E_EXPERTS / ESPLIT)     // 16 experts per wave
#define PSTRIDE (KSPLIT * E_EXPERTS) // 256 floats per token in partials

// ---------------------------------------------------------------------------
// Gates kernel — round-1 dataflow (lane=token, wave-uniform scalar W loads,
// zero LDS) + occupancy (4 waves/SIMD) + 4-deep register prefetch pipeline.
// Block = 256 threads = 4 waves = 4 expert-quarters of the SAME 64 tokens and
// SAME kc chunk (L1 reuse of x across waves). Grid = 256 tg x 4 kc = 1024.
// Each lane: 16 fp32 accumulators; per float4 of x: 64 v_fmac.
// FMA chain per expert is k-ascending within the chunk (matches rounds 1-2;
// reduce kernel preserves bias + kc0..kc3 order -> bit-identical logits).
// ---------------------------------------------------------------------------
__global__ __launch_bounds__(256) void gates_kernel(
    const float* __restrict__ x, const float* __restrict__ W,
    float* __restrict__ part) {
  const int tid = threadIdx.x;
  const int lane = tid & 63;
  const int eh = __builtin_amdgcn_readfirstlane(tid >> 6);  // expert quarter
  const int tg = blockIdx.x >> 2;
  const int kc = blockIdx.x & 3;
  const int t = tg * 64 + lane;
  const int kbase = kc * KCHUNK;

  const float* xp = x + (size_t)t * K_DIM + kbase;
  const float* wp = W + (size_t)kbase * E_EXPERTS + eh * EPW;

  float acc[EPW];
#pragma unroll
  for (int e = 0; e < EPW; ++e) acc[e] = 0.0f;

  float4 b0 = *reinterpret_cast<const float4*>(xp + 0);
  float4 b1 = *reinterpret_cast<const float4*>(xp + 4);
  float4 b2 = *reinterpret_cast<const float4*>(xp + 8);
  float4 b3 = *reinterpret_cast<const float4*>(xp + 12);

#define FMA4(bv, kofs)                                                        \
  do {                                                                        \
    const float* wr0 = wp + (size_t)(kofs)*E_EXPERTS;                         \
    float xs[4] = {bv.x, bv.y, bv.z, bv.w};                                   \
    _Pragma("unroll") for (int kk = 0; kk < 4; ++kk) {                        \
      const float* wr = wr0 + kk * E_EXPERTS;                                 \
      _Pragma("unroll") for (int e = 0; e < EPW; ++e)                         \
        acc[e] = fmaf(xs[kk], wr[e], acc[e]);                                 \
    }                                                                         \
  } while (0)

  // 512 k = 32 groups of 16; last group peeled (no prefetch -> no OOB reads)
  for (int g = 0; g < KCHUNK / 16 - 1; ++g) {
    const int k0 = g * 16;
    FMA4(b0, k0 + 0);  b0 = *reinterpret_cast<const float4*>(xp + k0 + 16);
    FMA4(b1, k0 + 4);  b1 = *reinterpret_cast<const float4*>(xp + k0 + 20);
    FMA4(b2, k0 + 8);  b2 = *reinterpret_cast<const float4*>(xp + k0 + 24);
    FMA4(b3, k0 + 12); b3 = *reinterpret_cast<const float4*>(xp + k0 + 28);
  }
  {
    const int k0 = KCHUNK - 16;
    FMA4(b0, k0 + 0);
    FMA4(b1, k0 + 4);
    FMA4(b2, k0 + 8);
    FMA4(b3, k0 + 12);
  }
#undef FMA4

  // epilogue: 4 float4 stores, contiguous 16 floats per lane
  float* p = part + (size_t)t * PSTRIDE + kc * E_EXPERTS + eh * EPW;
#pragma unroll
  for (int v = 0; v < EPW / 4; ++v) {
    *reinterpret_cast<float4*>(p + v * 4) =
        make_float4(acc[4 * v + 0], acc[4 * v + 1], acc[4 * v + 2],
                    acc[4 * v + 3]);
  }
}

// ---------------------------------------------------------------------------
// Reduce + bias + top-2 + softmax. Thread = token; 64 independent float4
// loads/thread (deep MLP), 1KB contiguous per thread. 256 blocks x 64 thr
// spreads one wave per CU. Math order identical to rounds 1-2 (passed).
// ---------------------------------------------------------------------------
__global__ __launch_bounds__(64) void reduce_topk_kernel(
    const float* __restrict__ part, const float* __restrict__ bias,
    float* __restrict__ out) {
  const int t = blockIdx.x * 64 + threadIdx.x;
  const float4* p = reinterpret_cast<const float4*>(part + (size_t)t * PSTRIDE);
  const float4* b4 = reinterpret_cast<const float4*>(bias);

  float m1 = -INFINITY, m2 = -INFINITY;
  int i1 = 0, i2 = 0;

#pragma unroll 4
  for (int e4 = 0; e4 < 16; ++e4) {
    float4 a = p[e4];        // kc = 0
    float4 b = p[16 + e4];   // kc = 1
    float4 c = p[32 + e4];   // kc = 2
    float4 d = p[48 + e4];   // kc = 3
    float4 bb = b4[e4];
    float g[4];
    g[0] = bb.x + a.x; g[0] += b.x; g[0] += c.x; g[0] += d.x;
    g[1] = bb.y + a.y; g[1] += b.y; g[1] += c.y; g[1] += d.y;
    g[2] = bb.z + a.z; g[2] += b.z; g[2] += c.z; g[2] += d.z;
    g[3] = bb.w + a.w; g[3] += b.w; g[3] += c.w; g[3] += d.w;
#pragma unroll
    for (int j = 0; j < 4; ++j) {
      int e = e4 * 4 + j;
      if (g[j] > m1) {
        m2 = m1; i2 = i1;
        m1 = g[j]; i1 = e;
      } else if (g[j] > m2) {
        m2 = g[j]; i2 = e;
      }
    }
  }

  float w0 = 1.0f / (1.0f + expf(m2 - m1));
  out[2 * t + 0] = w0;
  out[2 * t + 1] = 1.0f - w0;
  float* oidx = out + 2 * (size_t)M_TOKENS;
  oidx[2 * t + 0] = (float)i1;
  oidx[2 * t + 1] = (float)i2;
}

// ---------------------------------------------------------------------------
// Fallback (proven correct in round 1): fully fused, no workspace.
// ---------------------------------------------------------------------------
__global__ __launch_bounds__(64) void router_fused_kernel(
    const float* __restrict__ x, const float* __restrict__ W,
    const float* __restrict__ bias, float* __restrict__ out) {
  const int t = blockIdx.x * 64 + threadIdx.x;
  const float* xrow = x + (size_t)t * K_DIM;

  float acc[E_EXPERTS];
#pragma unroll
  for (int e = 0; e < E_EXPERTS; ++e) acc[e] = 0.0f;

  for (int k4 = 0; k4 < K_DIM; k4 += 4) {
    float4 xv = *reinterpret_cast<const float4*>(xrow + k4);
    float xs[4] = {xv.x, xv.y, xv.z, xv.w};
#pragma unroll
    for (int kk = 0; kk < 4; ++kk) {
      const float* wrow = W + (size_t)(k4 + kk) * E_EXPERTS;
#pragma unroll
      for (int e = 0; e < E_EXPERTS; ++e) acc[e] = fmaf(xs[kk], wrow[e], acc[e]);
    }
  }

  float m1 = -INFINITY, m2 = -INFINITY;
  int i1 = 0, i2 = 0;
#pragma unroll
  for (int e = 0; e < E_EXPERTS; ++e) {
    float g = acc[e] + bias[e];
    if (g > m1) {
      m2 = m1; i2 = i1;
      m1 = g; i1 = e;
    } else if (g > m2) {
      m2 = g; i2 = e;
    }
  }

  float w0 = 1.0f / (1.0f + expf(m2 - m1));
  out[2 * t + 0] = w0;
  out[2 * t + 1] = 1.0f - w0;
  float* oidx = out + 2 * (size_t)M_TOKENS;
  oidx[2 * t + 0] = (float)i1;
  oidx[2 * t + 1] = (float)i2;
}

extern "C" void kernel_launch(void* const* d_in, const int* in_sizes, int n_in,
                              void* d_out, int out_size, void* d_ws, size_t ws_size,
                              hipStream_t stream) {
  const float* x = (const float*)d_in[0];
  const float* W = (const float*)d_in[1];
  const float* b = (const float*)d_in[2];
  float* out = (float*)d_out;

  const size_t need = (size_t)M_TOKENS * PSTRIDE * sizeof(float);
  if (ws_size >= need) {
    float* part = (float*)d_ws;
    gates_kernel<<<(M_TOKENS / 64) * KSPLIT, 256, 0, stream>>>(x, W, part);
    reduce_topk_kernel<<<M_TOKENS / 64, 64, 0, stream>>>(part, b, out);
  } else {
    router_fused_kernel<<<M_TOKENS / 64, 64, 0, stream>>>(x, W, b, out);
  }
}